// Round 11
// baseline (562.761 us; speedup 1.0000x reference)
//
#include <hip/hip_runtime.h>
#include <cstddef>

#define N_NODES 50000
#define N_EDGES 800000
#define N_PAIRS 100000

typedef float floatx4 __attribute__((ext_vector_type(4)));
typedef _Float16 half2v __attribute__((ext_vector_type(2)));
typedef _Float16 half4v __attribute__((ext_vector_type(4)));
typedef _Float16 half8v __attribute__((ext_vector_type(8)));

// packed MFMA A/B-fragment layout: [tile16][kchunk32][lane][8] (fp16)
__device__ inline size_t packA(int m, int k, int K) {
  return ((size_t)((m >> 4) * (K >> 5) + (k >> 5)) << 9) +
         ((((unsigned)k >> 3) & 3) << 7) + ((m & 15) << 3) + (k & 7);
}

// ---------------- weight prep (fold + transpose + pack, fp16)
__device__ inline float fold_val(int l, int r, int j, const float* Wk, const float* Wq,
                                 const float* Wv, const float* att, const float* msg,
                                 const float* pri) {
  if (j >= 128 && j < 256) return Wq[(l * 128 + r) * 128 + (j - 128)];
  int jj = j & 127, hh = jj >> 4, e = jj & 15;
  const float* W = (j < 128) ? Wk : Wv;
  const float* T = (j < 128) ? att : msg;
  float s = 0.f;
#pragma unroll
  for (int d = 0; d < 16; d++)
    s += W[(l * 128 + r) * 128 + hh * 16 + d] * T[((l * 8 + hh) * 16 + d) * 16 + e];
  if (j < 128) s *= pri[l * 8 + hh] * 0.25f;
  return s;
}

// fused: wprep (blocks [0,880)) + edge-dst histogram (blocks [880, 880+3125))
__global__ void prep_fused(const float* __restrict__ W_in, const float* __restrict__ Wk,
                           const float* __restrict__ Wq, const float* __restrict__ Wv,
                           const float* __restrict__ att, const float* __restrict__ msg,
                           const float* __restrict__ pri, const float* __restrict__ Wa,
                           const float* __restrict__ W1, const float* __restrict__ W2,
                           _Float16* Wint, _Float16* Wcat, _Float16* Waf,
                           _Float16* W1f, _Float16* W2f,
                           const int* __restrict__ dst, int* __restrict__ deg, int E) {
  if (blockIdx.x >= 880) {
    int g = (blockIdx.x - 880) * 256 + threadIdx.x;
    if (g < E) atomicAdd(&deg[dst[g]], 1);
    return;
  }
  int gid = blockIdx.x * 256 + threadIdx.x;
  float v;
  _Float16* dt;
  size_t o;
  if (gid < 16384) {
    int n = gid >> 7, k = gid & 127;
    v = W_in[k * 128 + n];
    dt = Wint; o = packA(n, k, 128);
  } else if (gid < 163840) {
    int t = gid - 16384;
    int l = t / 49152, u = t - l * 49152;
    int n = u >> 7, k = u & 127;
    v = fold_val(l, k, n, Wk, Wq, Wv, att, msg, pri);
    dt = Wcat + (size_t)l * 49152;
    o = packA(n, k, 128);
  } else if (gid < 212992) {
    int t = gid - 163840;
    int l = t / 16384, u = t & 16383;
    int n = u >> 7, k = u & 127;
    v = Wa[(size_t)l * 16384 + k * 128 + n];
    dt = Waf + (size_t)l * 16384;
    o = packA(n, k, 128);
  } else if (gid < 221184) {
    int u = gid - 212992;
    int n = u >> 7, k = u & 127;
    v = W1[k * 64 + n];
    dt = W1f; o = packA(n, k, 128);
  } else if (gid < 225280) {
    int u = gid - 221184;
    int n = u >> 6, k = u & 63;
    v = (n < 32) ? W2[k * 32 + n] : 0.f;
    dt = W2f; o = packA(n, k, 64);
  } else {
    return;
  }
  dt[o] = (_Float16)v;
}

// ---------------- CSR scan stage A (padded-8 slots) + bucket histogram +
// per-256-node-bucket raw edge count (block b == bucket b, both 256-wide)
__global__ void scanA_kernel(const int* __restrict__ deg, int* __restrict__ offs,
                             int* __restrict__ bsum, int* __restrict__ bh,
                             int* __restrict__ bcnt, int n) {
  __shared__ int sm[256];
  __shared__ int lh[256];
  __shared__ int dsum;
  int t = threadIdx.x;
  int i = blockIdx.x * 256 + t;
  int dv = (i < n) ? deg[i] : 0;
  int v = (i < n) ? ((dv + 7) & ~7) : 0;
  if (t == 0) dsum = 0;
  sm[t] = v;
  __syncthreads();
  for (int off = 1; off < 256; off <<= 1) {
    int u = (t >= off) ? sm[t - off] : 0;
    __syncthreads();
    sm[t] += u;
    __syncthreads();
  }
  if (i < n) offs[i] = sm[t] - v;
  if (t == 255) bsum[blockIdx.x] = sm[255];
  // bucket histogram (bhist fused)
  lh[t] = 0;
  __syncthreads();
  if (i < n) atomicAdd(&lh[min(dv, 255)], 1);
  atomicAdd(&dsum, dv);
  __syncthreads();
  if (lh[t]) atomicAdd(&bh[t], lh[t]);
  if (t == 0) bcnt[blockIdx.x] = dsum;
}

// ---------------- fused scanC + bscatter + phase-A bucket-base init
__global__ void scanC_fused(int* __restrict__ offs, const int* __restrict__ bsum,
                            const int* __restrict__ bh, int* __restrict__ balloc,
                            const int* __restrict__ deg, int* __restrict__ cursor,
                            int* __restrict__ perm, const int* __restrict__ bcnt,
                            int* __restrict__ bcur2, int nb, int n) {
  __shared__ int sA[256], sB[256], bcurL[256], lh[256], lbase[256];
  int t = threadIdx.x;
  int i = blockIdx.x * 256 + t;
  int vA = (t < nb) ? bsum[t] : 0;
  sA[t] = vA;
  __syncthreads();
  for (int off = 1; off < 256; off <<= 1) {
    int u = (t >= off) ? sA[t - off] : 0;
    __syncthreads();
    sA[t] += u;
    __syncthreads();
  }
  int boffx = sA[blockIdx.x] - bsum[blockIdx.x];
  int vB = bh[255 - t];
  sB[t] = vB;
  __syncthreads();
  for (int off = 1; off < 256; off <<= 1) {
    int u = (t >= off) ? sB[t - off] : 0;
    __syncthreads();
    sB[t] += u;
    __syncthreads();
  }
  bcurL[255 - t] = sB[t] - vB;
  __syncthreads();
  int o = 0, dv = 0;
  if (i < n) {
    o = offs[i] + boffx;
    offs[i] = o;
    cursor[i] = o;
    dv = deg[i];
  }
  if (blockIdx.x == nb - 1 && t == nb - 1) offs[n] = sA[nb - 1];
  lh[t] = 0;
  __syncthreads();
  int b = 0, local = 0;
  if (i < n) {
    b = min(dv, 255);
    local = atomicAdd(&lh[b], 1);
  }
  __syncthreads();
  int cnt = lh[t];
  lbase[t] = cnt ? atomicAdd(&balloc[t], cnt) : 0;
  __syncthreads();
  if (i < n) perm[bcurL[b] + lbase[b] + local] = i;
  // phase-A bucket cursors: exclusive prefix over raw bucket counts (block 0)
  if (blockIdx.x == 0) {
    __shared__ int sC[256];
    int vC = (t < nb) ? bcnt[t] : 0;
    sC[t] = vC;
    __syncthreads();
    for (int off = 1; off < 256; off <<= 1) {
      int u = (t >= off) ? sC[t - off] : 0;
      __syncthreads();
      sC[t] += u;
      __syncthreads();
    }
    if (t < nb) bcur2[t] = sC[t] - vC;
  }
}

// ---------------- scatter phase A: LDS-aggregated binning into 196 dst>>8
// buckets (bucket-contiguous 12B triples -> near-payload write traffic).
__global__ __launch_bounds__(256) void scatterA_kernel(
    const int* __restrict__ src, const int* __restrict__ dst,
    const float* __restrict__ w, int* __restrict__ bcur2,
    int2* __restrict__ ebuk_sw, int* __restrict__ ebuk_d, int E) {
  __shared__ int lcnt[196], lbase[196];
  int t = threadIdx.x;
  for (int i = t; i < 196; i += 256) lcnt[i] = 0;
  __syncthreads();
  int g0 = blockIdx.x * 1024 + t;
  int dv[4], sv[4], wv[4], lr[4], bk[4];
#pragma unroll
  for (int e = 0; e < 4; e++) {
    int g = g0 + e * 256;
    bk[e] = -1;
    if (g < E) {
      dv[e] = dst[g];
      sv[e] = src[g];
      wv[e] = __float_as_int(w[g]);
      bk[e] = dv[e] >> 8;
      lr[e] = atomicAdd(&lcnt[bk[e]], 1);
    }
  }
  __syncthreads();
  for (int i = t; i < 196; i += 256)
    lbase[i] = lcnt[i] ? atomicAdd(&bcur2[i], lcnt[i]) : 0;
  __syncthreads();
#pragma unroll
  for (int e = 0; e < 4; e++) {
    if (bk[e] >= 0) {
      int pos = lbase[bk[e]] + lr[e];
      ebuk_d[pos] = dv[e];
      ebuk_sw[pos] = make_int2(sv[e], wv[e]);
    }
  }
}

// ---------------- scatter phase B: sequential bucketized read; eld writes land
// in a ~33KB per-bucket window (L2-resident -> full-line utilization).
__global__ void scatterB_kernel(const int2* __restrict__ ebuk_sw,
                                const int* __restrict__ ebuk_d,
                                int* __restrict__ cursor, int2* __restrict__ eld,
                                int E) {
  int g = blockIdx.x * blockDim.x + threadIdx.x;
  if (g < E) {
    int d = ebuk_d[g];
    int p = atomicAdd(&cursor[d], 1);
    eld[p] = ebuk_sw[g];
  }
}

// ---------------- per-node src-sort of edge lists (64-lane bitonic).
// Online softmax is order-independent -> sorting is a pure perf transform:
// all edge_agg waves then sweep src-space in ascending order, shrinking the
// instantaneous cross-wave gather window to ~per-XCD-L2 scale.
__global__ __launch_bounds__(256) void sort_eld_kernel(
    const int* __restrict__ poffs, int2* __restrict__ eld, int n) {
  int node = (blockIdx.x * 256 + threadIdx.x) >> 6;  // one 64-lane wave per node
  int lane = threadIdx.x & 63;
  if (node >= n) return;
  int beg = poffs[node], end = poffs[node + 1];
  int cnt = end - beg;
  if (cnt <= 8 || cnt > 64) return;  // 1-chunk lists need no order; >64 never occurs
  unsigned key = 0xFFFFFFFFu;        // sentinel src=-1 also maps here (sorts last)
  int wv = 0;
  if (lane < cnt) {
    int2 e = eld[beg + lane];
    key = (unsigned)e.x;
    wv = e.y;
  }
#pragma unroll
  for (int k = 2; k <= 64; k <<= 1) {
#pragma unroll
    for (int j = k >> 1; j >= 1; j >>= 1) {
      unsigned ok = (unsigned)__shfl_xor((int)key, j);
      int ow = __shfl_xor(wv, j);
      bool lower = (lane & j) == 0;
      bool asc = (lane & k) == 0;
      bool wantMin = (lower == asc);
      bool take = wantMin ? (ok < key) : (ok > key);
      if (take) { key = ok; wv = ow; }
    }
  }
  if (lane < cnt) eld[beg + lane] = make_int2((int)key, wv);
}

// ---------------- fused layer kernel: GEMM1 (h) -> LDS fragments -> GEMM2 (kqv)
// TWO adjacent 16-row tiles per wave (shared B fragments). No intra-wave fences
// (per-wave LDS, in-order DS ops; compiler auto-inserts data-use waits).
template <int FIRST>
__global__ __launch_bounds__(256) void fused_layer(
    const float* __restrict__ x, const _Float16* __restrict__ aggp,
    const _Float16* __restrict__ Wg1, const float* __restrict__ bias,
    const float* __restrict__ skipv, _Float16* __restrict__ hbuf,
    const _Float16* __restrict__ Wcat_l,
    _Float16* __restrict__ kwmv, _Float16* __restrict__ qbuf, int M) {
  int tid = threadIdx.x;
  int wave = tid >> 6, lane = tid & 63;
  int l16 = lane & 15, q = lane >> 4;
  int g = q, mloc = l16;
  int t0 = (blockIdx.x * 4 + wave) * 2;

  __shared__ _Float16 htile_s[4][2][2048];
  __shared__ float ldsT_s[4][16 * 68];
  float* myT = ldsT_s[wave];

  float alpha = 1.f, beta = 0.f;
  if (!FIRST) {
    float sv = *skipv;
    alpha = 1.f / (1.f + __expf(-sv));
    beta = 1.f - alpha;
  }

  floatx4 acc[2][8];
#pragma unroll
  for (int t = 0; t < 2; t++)
#pragma unroll
    for (int nt = 0; nt < 8; nt++) acc[t][nt] = (floatx4){0.f, 0.f, 0.f, 0.f};

#pragma unroll
  for (int kc = 0; kc < 4; kc++) {
    half8v a0, a1;
#pragma unroll
    for (int t = 0; t < 2; t++) {
      int tile = t0 + t;
      int tileC = (tile * 16 < M) ? tile : 0;
      half8v av;
      if (FIRST) {
        int row = min(tile * 16 + l16, M - 1);
        const float* p = x + (size_t)row * 128 + kc * 32 + q * 8;
        float4 u0 = *(const float4*)p, u1 = *(const float4*)(p + 4);
        float f[8] = {u0.x, u0.y, u0.z, u0.w, u1.x, u1.y, u1.z, u1.w};
#pragma unroll
        for (int i = 0; i < 8; i++) av[i] = (_Float16)f[i];
      } else {
        av = *(const half8v*)(aggp + (size_t)tileC * 2048 + (kc << 9) + lane * 8);
      }
      if (t == 0) a0 = av; else a1 = av;
    }
#pragma unroll
    for (int nt = 0; nt < 8; nt++) {
      half8v b = *(const half8v*)(Wg1 + (size_t)nt * 2048 + (kc << 9) + lane * 8);
      acc[0][nt] = __builtin_amdgcn_mfma_f32_16x16x32_f16(a0, b, acc[0][nt], 0, 0, 0);
      acc[1][nt] = __builtin_amdgcn_mfma_f32_16x16x32_f16(a1, b, acc[1][nt], 0, 0, 0);
    }
  }

#pragma unroll
  for (int t = 0; t < 2; t++) {
    int tile = t0 + t;
    bool alive = tile * 16 < M;
    int tileC = alive ? tile : 0;
#pragma unroll
    for (int p = 0; p < 2; p++) {
#pragma unroll
      for (int ntl = 0; ntl < 4; ntl++)
#pragma unroll
        for (int r = 0; r < 4; r++)
          myT[(q * 4 + r) * 68 + ntl * 16 + l16] = acc[t][p * 4 + ntl][r];
#pragma unroll
      for (int kc2 = 0; kc2 < 2; kc2++) {
        const float* rp = myT + mloc * 68 + kc2 * 32 + g * 8;
        floatx4 v0 = *(const floatx4*)rp;
        floatx4 v1 = *(const floatx4*)(rp + 4);
        float vals[8] = {v0[0], v0[1], v0[2], v0[3], v1[0], v1[1], v1[2], v1[3]};
        int col0 = p * 64 + kc2 * 32 + g * 8;
        size_t pbaseL = ((size_t)(tileC * 4 + (col0 >> 5)) << 9) + (size_t)lane * 8;
        if (FIRST) {
          float4 bb0 = *(const float4*)&bias[col0];
          float4 bb1 = *(const float4*)&bias[col0 + 4];
          float bbv[8] = {bb0.x, bb0.y, bb0.z, bb0.w, bb1.x, bb1.y, bb1.z, bb1.w};
#pragma unroll
          for (int j = 0; j < 8; j++) vals[j] = fmaxf(vals[j] + bbv[j], 0.f);
        } else {
          half8v hv = *(const half8v*)(hbuf + pbaseL);
#pragma unroll
          for (int j = 0; j < 8; j++)
            vals[j] = fmaxf(alpha * vals[j] + beta * (float)hv[j], 0.f);
        }
        half8v h8;
#pragma unroll
        for (int j = 0; j < 8; j++) h8[j] = (_Float16)vals[j];
        *(half8v*)(&htile_s[wave][t][0] + (((p * 2 + kc2) << 9) + (g << 7) + (mloc << 3))) = h8;
        if (alive) *(half8v*)(hbuf + pbaseL) = h8;
      }
    }
  }

  for (int c = 0; c < 6; c++) {
    floatx4 acc2[2][4];
#pragma unroll
    for (int t = 0; t < 2; t++)
#pragma unroll
      for (int nt = 0; nt < 4; nt++) acc2[t][nt] = (floatx4){0.f, 0.f, 0.f, 0.f};
#pragma unroll
    for (int kc = 0; kc < 4; kc++) {
      half8v af0 = *(const half8v*)(&htile_s[wave][0][0] + ((kc << 9) + lane * 8));
      half8v af1 = *(const half8v*)(&htile_s[wave][1][0] + ((kc << 9) + lane * 8));
#pragma unroll
      for (int nt = 0; nt < 4; nt++) {
        half8v b = *(const half8v*)(Wcat_l + (size_t)(c * 4 + nt) * 2048 + (kc << 9) + lane * 8);
        acc2[0][nt] = __builtin_amdgcn_mfma_f32_16x16x32_f16(af0, b, acc2[0][nt], 0, 0, 0);
        acc2[1][nt] = __builtin_amdgcn_mfma_f32_16x16x32_f16(af1, b, acc2[1][nt], 0, 0, 0);
      }
    }
#pragma unroll
    for (int t = 0; t < 2; t++) {
      int tile = t0 + t;
      bool alive = tile * 16 < M;
      int m0 = tile * 16;
#pragma unroll
      for (int ntl = 0; ntl < 4; ntl++)
#pragma unroll
        for (int r = 0; r < 4; r++)
          myT[(q * 4 + r) * 68 + ntl * 16 + l16] = acc2[t][ntl][r];
      if (alive) {
        int row = m0 + mloc;
#pragma unroll
        for (int kc2 = 0; kc2 < 2; kc2++) {
          const float* rp = myT + mloc * 68 + kc2 * 32 + g * 8;
          floatx4 v0 = *(const floatx4*)rp;
          floatx4 v1 = *(const floatx4*)(rp + 4);
          int col0 = c * 64 + kc2 * 32 + g * 8;
          int region = col0 >> 7;  // 0 kw, 1 q, 2 mv
          if (region == 1) {
            half8v h8;
#pragma unroll
            for (int j = 0; j < 4; j++) {
              h8[j] = (_Float16)v0[j];
              h8[j + 4] = (_Float16)v1[j];
            }
            *(half8v*)&qbuf[(size_t)row * 128 + (col0 - 128)] = h8;
          } else {
            int cc = col0 & 127;
            size_t base = (size_t)row * 256 + (size_t)(cc >> 2) * 8 + (region == 2 ? 4 : 0);
            half4v h0, h1;
#pragma unroll
            for (int j = 0; j < 4; j++) {
              h0[j] = (_Float16)v0[j];
              h1[j] = (_Float16)v1[j];
            }
            *(half4v*)&kwmv[base] = h0;
            *(half4v*)&kwmv[base + 8] = h1;
          }
        }
      }
    }
  }
}

// ---------------- last Wa GEMM (2 tiles/wave)
__global__ __launch_bounds__(256) void gemm_last(
    const _Float16* __restrict__ aggp, const _Float16* __restrict__ Wg1,
    const float* __restrict__ skipv, const _Float16* __restrict__ hbuf,
    float* __restrict__ hfinal, _Float16* __restrict__ hrow, int M) {
  int tid = threadIdx.x;
  int wave = tid >> 6, lane = tid & 63;
  int l16 = lane & 15, q = lane >> 4;
  int g = q, mloc = l16;
  int t0 = (blockIdx.x * 4 + wave) * 2;

  __shared__ float ldsT_s[4][16 * 68];
  float* myT = ldsT_s[wave];

  float sv = *skipv;
  float alpha = 1.f / (1.f + __expf(-sv));
  float beta = 1.f - alpha;

  floatx4 acc[2][8];
#pragma unroll
  for (int t = 0; t < 2; t++)
#pragma unroll
    for (int nt = 0; nt < 8; nt++) acc[t][nt] = (floatx4){0.f, 0.f, 0.f, 0.f};

#pragma unroll
  for (int kc = 0; kc < 4; kc++) {
    int tC0 = (t0 * 16 < M) ? t0 : 0;
    int tC1 = ((t0 + 1) * 16 < M) ? (t0 + 1) : 0;
    half8v a0 = *(const half8v*)(aggp + (size_t)tC0 * 2048 + (kc << 9) + lane * 8);
    half8v a1 = *(const half8v*)(aggp + (size_t)tC1 * 2048 + (kc << 9) + lane * 8);
#pragma unroll
    for (int nt = 0; nt < 8; nt++) {
      half8v b = *(const half8v*)(Wg1 + (size_t)nt * 2048 + (kc << 9) + lane * 8);
      acc[0][nt] = __builtin_amdgcn_mfma_f32_16x16x32_f16(a0, b, acc[0][nt], 0, 0, 0);
      acc[1][nt] = __builtin_amdgcn_mfma_f32_16x16x32_f16(a1, b, acc[1][nt], 0, 0, 0);
    }
  }

#pragma unroll
  for (int t = 0; t < 2; t++) {
    int tile = t0 + t;
    bool alive = tile * 16 < M;
    int m0 = tile * 16;
#pragma unroll
    for (int p = 0; p < 2; p++) {
#pragma unroll
      for (int ntl = 0; ntl < 4; ntl++)
#pragma unroll
        for (int r = 0; r < 4; r++)
          myT[(q * 4 + r) * 68 + ntl * 16 + l16] = acc[t][p * 4 + ntl][r];
      if (alive) {
        int row = m0 + mloc;
#pragma unroll
        for (int kc2 = 0; kc2 < 2; kc2++) {
          const float* rp = myT + mloc * 68 + kc2 * 32 + g * 8;
          floatx4 v0 = *(const floatx4*)rp;
          floatx4 v1 = *(const floatx4*)(rp + 4);
          float vals[8] = {v0[0], v0[1], v0[2], v0[3], v1[0], v1[1], v1[2], v1[3]};
          int col0 = p * 64 + kc2 * 32 + g * 8;
          size_t pbase = ((size_t)(tile * 4 + (col0 >> 5)) << 9) + (size_t)lane * 8;
          half8v hv = *(const half8v*)(hbuf + pbase);
#pragma unroll
          for (int j = 0; j < 8; j++) vals[j] = alpha * vals[j] + beta * (float)hv[j];
          *(float4*)&hfinal[(size_t)row * 128 + col0] =
              make_float4(vals[0], vals[1], vals[2], vals[3]);
          *(float4*)&hfinal[(size_t)row * 128 + col0 + 4] =
              make_float4(vals[4], vals[5], vals[6], vals[7]);
          half8v h8;
#pragma unroll
          for (int j = 0; j < 8; j++) h8[j] = (_Float16)vals[j];
          *(half8v*)&hrow[(size_t)row * 128 + col0] = h8;
        }
      }
    }
  }
}

// ---------------- fused predictor (2 tiles/wave)
__global__ __launch_bounds__(256) void pred_fused(
    const _Float16* __restrict__ hrow,
    const int* __restrict__ ps, const int* __restrict__ pd,
    const int* __restrict__ ns, const int* __restrict__ nd,
    const _Float16* __restrict__ W1f, const float* __restrict__ b1,
    const _Float16* __restrict__ W2f, const float* __restrict__ b2,
    const float* __restrict__ W3, const float* __restrict__ b3,
    float* __restrict__ outd, int M) {
  int tid = threadIdx.x;
  int wave = tid >> 6, lane = tid & 63;
  int l16 = lane & 15, q = lane >> 4;
  int g = q, mloc = l16;
  int t0 = (blockIdx.x * 4 + wave) * 2;

  __shared__ _Float16 t1_s[4][2][1024];
  __shared__ float ldsT_s[4][16 * 68];
  float* myT = ldsT_s[wave];

  int pa[2], pb[2];
#pragma unroll
  for (int t = 0; t < 2; t++) {
    int gr = min((t0 + t) * 16 + l16, M - 1);
    bool pos = gr < N_PAIRS;
    int idx = pos ? gr : gr - N_PAIRS;
    pa[t] = pos ? ps[idx] : ns[idx];
    pb[t] = pos ? pd[idx] : nd[idx];
  }

  floatx4 acc1[2][4];
#pragma unroll
  for (int t = 0; t < 2; t++)
#pragma unroll
    for (int nt = 0; nt < 4; nt++) acc1[t][nt] = (floatx4){0.f, 0.f, 0.f, 0.f};

#pragma unroll
  for (int kc = 0; kc < 4; kc++) {
    int kbase = kc * 32 + q * 8;
    half8v a0, a1;
#pragma unroll
    for (int t = 0; t < 2; t++) {
      half8v ha = *(const half8v*)(hrow + (size_t)pa[t] * 128 + kbase);
      half8v hb = *(const half8v*)(hrow + (size_t)pb[t] * 128 + kbase);
      half8v av = ha * hb;
      if (t == 0) a0 = av; else a1 = av;
    }
#pragma unroll
    for (int nt = 0; nt < 4; nt++) {
      half8v b = *(const half8v*)(W1f + (size_t)nt * 2048 + (kc << 9) + lane * 8);
      acc1[0][nt] = __builtin_amdgcn_mfma_f32_16x16x32_f16(a0, b, acc1[0][nt], 0, 0, 0);
      acc1[1][nt] = __builtin_amdgcn_mfma_f32_16x16x32_f16(a1, b, acc1[1][nt], 0, 0, 0);
    }
  }

#pragma unroll
  for (int t = 0; t < 2; t++) {
#pragma unroll
    for (int ntl = 0; ntl < 4; ntl++)
#pragma unroll
      for (int r = 0; r < 4; r++)
        myT[(q * 4 + r) * 68 + ntl * 16 + l16] = acc1[t][ntl][r];
#pragma unroll
    for (int kc2 = 0; kc2 < 2; kc2++) {
      const float* rp = myT + mloc * 68 + kc2 * 32 + g * 8;
      floatx4 v0 = *(const floatx4*)rp;
      floatx4 v1 = *(const floatx4*)(rp + 4);
      float vals[8] = {v0[0], v0[1], v0[2], v0[3], v1[0], v1[1], v1[2], v1[3]};
      int col0 = kc2 * 32 + g * 8;
      float4 bb0 = *(const float4*)&b1[col0];
      float4 bb1 = *(const float4*)&b1[col0 + 4];
      float bbv[8] = {bb0.x, bb0.y, bb0.z, bb0.w, bb1.x, bb1.y, bb1.z, bb1.w};
      half8v h8;
#pragma unroll
      for (int j = 0; j < 8; j++) {
        float v = vals[j] + bbv[j];
        v = v > 0.f ? v : 0.2f * v;
        h8[j] = (_Float16)v;
      }
      *(half8v*)(&t1_s[wave][t][0] + ((kc2 << 9) + (g << 7) + (mloc << 3))) = h8;
    }
  }

  floatx4 acc2[2][2];
#pragma unroll
  for (int t = 0; t < 2; t++)
#pragma unroll
    for (int nt = 0; nt < 2; nt++) acc2[t][nt] = (floatx4){0.f, 0.f, 0.f, 0.f};
#pragma unroll
  for (int kc = 0; kc < 2; kc++) {
    half8v af0 = *(const half8v*)(&t1_s[wave][0][0] + ((kc << 9) + lane * 8));
    half8v af1 = *(const half8v*)(&t1_s[wave][1][0] + ((kc << 9) + lane * 8));
#pragma unroll
    for (int nt = 0; nt < 2; nt++) {
      half8v b = *(const half8v*)(W2f + (size_t)nt * 1024 + (kc << 9) + lane * 8);
      acc2[0][nt] = __builtin_amdgcn_mfma_f32_16x16x32_f16(af0, b, acc2[0][nt], 0, 0, 0);
      acc2[1][nt] = __builtin_amdgcn_mfma_f32_16x16x32_f16(af1, b, acc2[1][nt], 0, 0, 0);
    }
  }

  float bw[2], wv[2];
#pragma unroll
  for (int nt = 0; nt < 2; nt++) {
    int col = nt * 16 + l16;
    bw[nt] = b2[col];
    wv[nt] = W3[col];
  }
  float b3v = b3[0];
#pragma unroll
  for (int t = 0; t < 2; t++) {
    int m0 = (t0 + t) * 16;
    bool alive = m0 < M;
#pragma unroll
    for (int r = 0; r < 4; r++) {
      float partial = 0.f;
#pragma unroll
      for (int nt = 0; nt < 2; nt++) {
        float v = acc2[t][nt][r] + bw[nt];
        v = v > 0.f ? v : 0.2f * v;
        partial += v * wv[nt];
      }
      partial += __shfl_xor(partial, 1);
      partial += __shfl_xor(partial, 2);
      partial += __shfl_xor(partial, 4);
      partial += __shfl_xor(partial, 8);
      int row = m0 + q * 4 + r;
      if (l16 == 0 && alive && row < M) outd[row] = partial + b3v;
    }
  }
}

// ---------------- per-destination online-softmax aggregation [R2 best, unchanged]
__global__ __launch_bounds__(256) void edge_agg_kernel(
    const _Float16* __restrict__ kwmv, const _Float16* __restrict__ qbuf,
    const int* __restrict__ poffs, const int2* __restrict__ eld,
    const int* __restrict__ perm,
    _Float16* __restrict__ agg, int n) {
  int hw = (blockIdx.x * 256 + threadIdx.x) >> 5;
  int stride = gridDim.x << 3;
  int c4 = threadIdx.x & 31;
  int ch = c4 << 2;
  for (int gw = hw; gw < n; gw += stride) {
    int node = perm[gw];
    half4v qv = *(const half4v*)&qbuf[(size_t)node * 128 + ch];
    half2v q01 = {qv[0], qv[1]}, q23 = {qv[2], qv[3]};
    float m = -1e30f, s = 0.f;
    float a0 = 0.f, a1 = 0.f, a2 = 0.f, a3 = 0.f;
    int beg = poffs[node], end = poffs[node + 1];
    if (beg < end) {
      int2 e0[8], e1[8], e2[8];
      half8v g0[8], g1[8];
#pragma unroll
      for (int i = 0; i < 8; i++) e0[i] = eld[beg + i];
#pragma unroll
      for (int i = 0; i < 8; i++)
        g0[i] = *(const half8v*)&kwmv[(size_t)max(e0[i].x, 0) * 256 + (size_t)c4 * 8];
#pragma unroll
      for (int i = 0; i < 8; i++) e1[i] = eld[beg + 8 + i];
      int j = beg;
      for (; j + 8 < end; j += 8) {
#pragma unroll
        for (int i = 0; i < 8; i++)
          g1[i] = *(const half8v*)&kwmv[(size_t)max(e1[i].x, 0) * 256 + (size_t)c4 * 8];
#pragma unroll
        for (int i = 0; i < 8; i++) e2[i] = eld[j + 16 + i];
        float p[8];
#pragma unroll
        for (int i = 0; i < 8; i++) {
          half2v k01 = {g0[i][0], g0[i][1]}, k23 = {g0[i][2], g0[i][3]};
          float d = __builtin_amdgcn_fdot2(
              k01, q01, __builtin_amdgcn_fdot2(k23, q23, 0.f, false), false);
          d += __shfl_xor(d, 1);
          d += __shfl_xor(d, 2);
          p[i] = (e0[i].x >= 0) ? d : -1e30f;
        }
        float nm = m;
#pragma unroll
        for (int i = 0; i < 8; i++) nm = fmaxf(nm, p[i]);
        float sc = __expf(m - nm);
        float t[8];
        float ssum = 0.f;
#pragma unroll
        for (int i = 0; i < 8; i++) {
          t[i] = __expf(p[i] - nm);
          ssum += t[i];
        }
        s = s * sc + ssum;
        a0 *= sc; a1 *= sc; a2 *= sc; a3 *= sc;
#pragma unroll
        for (int i = 0; i < 8; i++) {
          float w = (e0[i].x >= 0) ? __int_as_float(e0[i].y) : 0.f;
          float f = t[i] * w;
          a0 += f * (float)g0[i][4];
          a1 += f * (float)g0[i][5];
          a2 += f * (float)g0[i][6];
          a3 += f * (float)g0[i][7];
        }
        m = nm;
#pragma unroll
        for (int i = 0; i < 8; i++) {
          e0[i] = e1[i];
          e1[i] = e2[i];
          g0[i] = g1[i];
        }
      }
      {
        float p[8];
#pragma unroll
        for (int i = 0; i < 8; i++) {
          half2v k01 = {g0[i][0], g0[i][1]}, k23 = {g0[i][2], g0[i][3]};
          float d = __builtin_amdgcn_fdot2(
              k01, q01, __builtin_amdgcn_fdot2(k23, q23, 0.f, false), false);
          d += __shfl_xor(d, 1);
          d += __shfl_xor(d, 2);
          p[i] = (e0[i].x >= 0) ? d : -1e30f;
        }
        float nm = m;
#pragma unroll
        for (int i = 0; i < 8; i++) nm = fmaxf(nm, p[i]);
        float sc = __expf(m - nm);
        float t[8];
        float ssum = 0.f;
#pragma unroll
        for (int i = 0; i < 8; i++) {
          t[i] = __expf(p[i] - nm);
          ssum += t[i];
        }
        s = s * sc + ssum;
        a0 *= sc; a1 *= sc; a2 *= sc; a3 *= sc;
#pragma unroll
        for (int i = 0; i < 8; i++) {
          float w = (e0[i].x >= 0) ? __int_as_float(e0[i].y) : 0.f;
          float f = t[i] * w;
          a0 += f * (float)g0[i][4];
          a1 += f * (float)g0[i][5];
          a2 += f * (float)g0[i][6];
          a3 += f * (float)g0[i][7];
        }
      }
    }
    float inv = (s > 0.f) ? 1.f / s : 0.f;
    half4v out4;
    out4[0] = (_Float16)(a0 * inv);
    out4[1] = (_Float16)(a1 * inv);
    out4[2] = (_Float16)(a2 * inv);
    out4[3] = (_Float16)(a3 * inv);
    *(half4v*)&agg[packA(node, ch, 128)] = out4;
  }
}

extern "C" void kernel_launch(void* const* d_in, const int* in_sizes, int n_in,
                              void* d_out, int out_size, void* d_ws, size_t ws_size,
                              hipStream_t stream) {
  const float* x        = (const float*)d_in[0];
  const int*   edge_src = (const int*)d_in[1];
  const int*   edge_dst = (const int*)d_in[2];
  const float* edge_w   = (const float*)d_in[3];
  const int*   pos_src  = (const int*)d_in[4];
  const int*   pos_dst  = (const int*)d_in[5];
  const int*   neg_src  = (const int*)d_in[6];
  const int*   neg_dst  = (const int*)d_in[7];
  const float* W_in     = (const float*)d_in[8];
  const float* b_in     = (const float*)d_in[9];
  const float* Wk       = (const float*)d_in[10];
  const float* Wq       = (const float*)d_in[11];
  const float* Wv       = (const float*)d_in[12];
  const float* att_w    = (const float*)d_in[13];
  const float* msg_w    = (const float*)d_in[14];
  const float* pri      = (const float*)d_in[15];
  const float* Wa       = (const float*)d_in[16];
  const float* skip     = (const float*)d_in[17];
  const float* W1       = (const float*)d_in[18];
  const float* b1       = (const float*)d_in[19];
  const float* W2       = (const float*)d_in[20];
  const float* b2       = (const float*)d_in[21];
  const float* W3       = (const float*)d_in[22];
  const float* b3       = (const float*)d_in[23];
  float* out = (float*)d_out;

  // ---- workspace layout (bytes), ~91 MB
  char* W = (char*)d_ws;
  _Float16*  qbuf   = (_Float16*)(W + 0);          // 12,800,000
  _Float16*  kwmv   = (_Float16*)(W + 12800000);   // 25,600,000
  _Float16*  hbuf   = (_Float16*)(W + 38400000);   // 12,800,000 (packed h)
  _Float16*  agg    = (_Float16*)(W + 51200000);   // 12,800,000
  _Float16*  Wint   = (_Float16*)(W + 64000000);   // 32,768
  _Float16*  Wcat   = (_Float16*)(W + 64032768);   // 294,912
  _Float16*  Waf    = (_Float16*)(W + 64327680);   // 98,304
  _Float16*  W1f    = (_Float16*)(W + 64425984);   // 16,384
  _Float16*  W2f    = (_Float16*)(W + 64442368);   // 8,192
  int2*      eld    = (int2*)(W + 64450560);       // 12,800,000 (padded-8 edges)
  int*       deg    = (int*)(W + 77250560);        // 200,000
  int*       bh     = (int*)(W + 77450560);        // 1,024   (adjacent: one memset)
  int*       balloc = (int*)(W + 77451584);        // 1,024
  int*       poffs  = (int*)(W + 77452608);        // 200,016
  int*       cursor = (int*)(W + 77652624);        // 200,000
  int*       perm   = (int*)(W + 77852624);        // 200,000
  int*       bsum   = (int*)(W + 78052624);        // 1,024
  int*       bcnt   = (int*)(W + 78053648);        // 1,024
  int*       bcur2  = (int*)(W + 78054672);        // 1,024
  _Float16*  hrow   = (_Float16*)(W + 78055696);   // 12,800,000 (fp16 row-major hfinal)
  float* hfinal = out + 2 * N_PAIRS;

  // ebuk staging aliases qbuf region (dead until fused_layer<1> writes qbuf)
  int2* ebuk_sw = (int2*)(W + 0);        // 6,400,000
  int*  ebuk_d  = (int*)(W + 6400000);   // 3,200,000

  hipMemsetAsync(deg, 0, 202048, stream);
  hipMemsetAsync(eld, 0xFF, 9600000, stream);

  prep_fused<<<4005, 256, 0, stream>>>(W_in, Wk, Wq, Wv, att_w, msg_w, pri, Wa, W1, W2,
                                       Wint, Wcat, Waf, W1f, W2f,
                                       edge_dst, deg, N_EDGES);
  scanA_kernel<<<196, 256, 0, stream>>>(deg, poffs, bsum, bh, bcnt, N_NODES);
  scanC_fused<<<196, 256, 0, stream>>>(poffs, bsum, bh, balloc, deg, cursor, perm,
                                       bcnt, bcur2, 196, N_NODES);
  scatterA_kernel<<<782, 256, 0, stream>>>(edge_src, edge_dst, edge_w, bcur2,
                                           ebuk_sw, ebuk_d, N_EDGES);
  scatterB_kernel<<<(N_EDGES + 255) / 256, 256, 0, stream>>>(
      ebuk_sw, ebuk_d, cursor, eld, N_EDGES);
  // src-sort each node's edge list (pure perf: L2 temporal locality in edge_agg)
  sort_eld_kernel<<<12500, 256, 0, stream>>>(poffs, eld, N_NODES);

  // layer 0
  fused_layer<1><<<391, 256, 0, stream>>>(x, nullptr, Wint, b_in, nullptr, hbuf,
                                          Wcat, kwmv, qbuf, N_NODES);
  edge_agg_kernel<<<2048, 256, 0, stream>>>(kwmv, qbuf, poffs, eld, perm, agg, N_NODES);
  // layer 1
  fused_layer<0><<<391, 256, 0, stream>>>(nullptr, agg, Waf, nullptr, skip + 0, hbuf,
                                          Wcat + 49152, kwmv, qbuf, N_NODES);
  edge_agg_kernel<<<2048, 256, 0, stream>>>(kwmv, qbuf, poffs, eld, perm, agg, N_NODES);
  // layer 2
  fused_layer<0><<<391, 256, 0, stream>>>(nullptr, agg, Waf + 16384, nullptr, skip + 1,
                                          hbuf, Wcat + 98304, kwmv, qbuf, N_NODES);
  edge_agg_kernel<<<2048, 256, 0, stream>>>(kwmv, qbuf, poffs, eld, perm, agg, N_NODES);
  // final
  gemm_last<<<391, 256, 0, stream>>>(agg, Waf + 32768, skip + 2, hbuf,
                                     hfinal, hrow, N_NODES);
  pred_fused<<<1563, 256, 0, stream>>>(hrow, pos_src, pos_dst, neg_src, neg_dst,
                                       W1f, b1, W2f, b2, W3, b3, out, 2 * N_PAIRS);
}

// Round 13
// 534.863 us; speedup vs baseline: 1.0522x; 1.0522x over previous
//
#include <hip/hip_runtime.h>
#include <cstddef>

#define N_NODES 50000
#define N_EDGES 800000
#define N_PAIRS 100000

typedef float floatx4 __attribute__((ext_vector_type(4)));
typedef _Float16 half2v __attribute__((ext_vector_type(2)));
typedef _Float16 half4v __attribute__((ext_vector_type(4)));
typedef _Float16 half8v __attribute__((ext_vector_type(8)));

// packed MFMA A/B-fragment layout: [tile16][kchunk32][lane][8] (fp16)
__device__ inline size_t packA(int m, int k, int K) {
  return ((size_t)((m >> 4) * (K >> 5) + (k >> 5)) << 9) +
         ((((unsigned)k >> 3) & 3) << 7) + ((m & 15) << 3) + (k & 7);
}

// ---------------- weight prep (fold + transpose + pack, fp16)
__device__ inline float fold_val(int l, int r, int j, const float* Wk, const float* Wq,
                                 const float* Wv, const float* att, const float* msg,
                                 const float* pri) {
  if (j >= 128 && j < 256) return Wq[(l * 128 + r) * 128 + (j - 128)];
  int jj = j & 127, hh = jj >> 4, e = jj & 15;
  const float* W = (j < 128) ? Wk : Wv;
  const float* T = (j < 128) ? att : msg;
  float s = 0.f;
#pragma unroll
  for (int d = 0; d < 16; d++)
    s += W[(l * 128 + r) * 128 + hh * 16 + d] * T[((l * 8 + hh) * 16 + d) * 16 + e];
  if (j < 128) s *= pri[l * 8 + hh] * 0.25f;
  return s;
}

// fused: wprep (blocks [0,880)) + edge-dst histogram (blocks [880, 880+3125))
__global__ void prep_fused(const float* __restrict__ W_in, const float* __restrict__ Wk,
                           const float* __restrict__ Wq, const float* __restrict__ Wv,
                           const float* __restrict__ att, const float* __restrict__ msg,
                           const float* __restrict__ pri, const float* __restrict__ Wa,
                           const float* __restrict__ W1, const float* __restrict__ W2,
                           _Float16* Wint, _Float16* Wcat, _Float16* Waf,
                           _Float16* W1f, _Float16* W2f,
                           const int* __restrict__ dst, int* __restrict__ deg, int E) {
  if (blockIdx.x >= 880) {
    int g = (blockIdx.x - 880) * 256 + threadIdx.x;
    if (g < E) atomicAdd(&deg[dst[g]], 1);
    return;
  }
  int gid = blockIdx.x * 256 + threadIdx.x;
  float v;
  _Float16* dt;
  size_t o;
  if (gid < 16384) {
    int n = gid >> 7, k = gid & 127;
    v = W_in[k * 128 + n];
    dt = Wint; o = packA(n, k, 128);
  } else if (gid < 163840) {
    int t = gid - 16384;
    int l = t / 49152, u = t - l * 49152;
    int n = u >> 7, k = u & 127;
    v = fold_val(l, k, n, Wk, Wq, Wv, att, msg, pri);
    dt = Wcat + (size_t)l * 49152;
    o = packA(n, k, 128);
  } else if (gid < 212992) {
    int t = gid - 163840;
    int l = t / 16384, u = t & 16383;
    int n = u >> 7, k = u & 127;
    v = Wa[(size_t)l * 16384 + k * 128 + n];
    dt = Waf + (size_t)l * 16384;
    o = packA(n, k, 128);
  } else if (gid < 221184) {
    int u = gid - 212992;
    int n = u >> 7, k = u & 127;
    v = W1[k * 64 + n];
    dt = W1f; o = packA(n, k, 128);
  } else if (gid < 225280) {
    int u = gid - 221184;
    int n = u >> 6, k = u & 63;
    v = (n < 32) ? W2[k * 32 + n] : 0.f;
    dt = W2f; o = packA(n, k, 64);
  } else {
    return;
  }
  dt[o] = (_Float16)v;
}

// ---------------- CSR scan stage A (padded-8 slots) + degree-bucket histogram
__global__ void scanA_kernel(const int* __restrict__ deg, int* __restrict__ offs,
                             int* __restrict__ bsum, int* __restrict__ bh, int n) {
  __shared__ int sm[256];
  __shared__ int lh[256];
  int t = threadIdx.x;
  int i = blockIdx.x * 256 + t;
  int dv = (i < n) ? deg[i] : 0;
  int v = (i < n) ? ((dv + 7) & ~7) : 0;
  sm[t] = v;
  __syncthreads();
  for (int off = 1; off < 256; off <<= 1) {
    int u = (t >= off) ? sm[t - off] : 0;
    __syncthreads();
    sm[t] += u;
    __syncthreads();
  }
  if (i < n) offs[i] = sm[t] - v;
  if (t == 255) bsum[blockIdx.x] = sm[255];
  // bucket histogram (bhist fused)
  lh[t] = 0;
  __syncthreads();
  if (i < n) atomicAdd(&lh[min(dv, 255)], 1);
  __syncthreads();
  if (lh[t]) atomicAdd(&bh[t], lh[t]);
}

// ---------------- fused scanC + bscatter (redundant in-block tiny scans)
__global__ void scanC_fused(int* __restrict__ offs, const int* __restrict__ bsum,
                            const int* __restrict__ bh, int* __restrict__ balloc,
                            const int* __restrict__ deg, int* __restrict__ cursor,
                            int* __restrict__ perm, int nb, int n) {
  __shared__ int sA[256], sB[256], bcurL[256], lh[256], lbase[256];
  int t = threadIdx.x;
  int i = blockIdx.x * 256 + t;
  int vA = (t < nb) ? bsum[t] : 0;
  sA[t] = vA;
  __syncthreads();
  for (int off = 1; off < 256; off <<= 1) {
    int u = (t >= off) ? sA[t - off] : 0;
    __syncthreads();
    sA[t] += u;
    __syncthreads();
  }
  int boffx = sA[blockIdx.x] - bsum[blockIdx.x];
  int vB = bh[255 - t];
  sB[t] = vB;
  __syncthreads();
  for (int off = 1; off < 256; off <<= 1) {
    int u = (t >= off) ? sB[t - off] : 0;
    __syncthreads();
    sB[t] += u;
    __syncthreads();
  }
  bcurL[255 - t] = sB[t] - vB;
  __syncthreads();
  int o = 0, dv = 0;
  if (i < n) {
    o = offs[i] + boffx;
    offs[i] = o;
    cursor[i] = o;
    dv = deg[i];
  }
  if (blockIdx.x == nb - 1 && t == nb - 1) offs[n] = sA[nb - 1];
  lh[t] = 0;
  __syncthreads();
  int b = 0, local = 0;
  if (i < n) {
    b = min(dv, 255);
    local = atomicAdd(&lh[b], 1);
  }
  __syncthreads();
  int cnt = lh[t];
  lbase[t] = cnt ? atomicAdd(&balloc[t], cnt) : 0;
  __syncthreads();
  if (i < n) perm[bcurL[b] + lbase[b] + local] = i;
}

// ---------------- scatter: naive placement + NONTEMPORAL eld store
// (random 8B stores each allocate a 64B L2 line -> 51MB WRITE; nt streams past
// the allocate path). int2 packed into a 64-bit int: low word = .x (src),
// high word = .y (wbits) -- little-endian layout matches int2.
__global__ void scatter_kernel(const int* __restrict__ src, const int* __restrict__ dst,
                               const float* __restrict__ w, int* __restrict__ cursor,
                               int2* __restrict__ eld, int E) {
  int g = blockIdx.x * blockDim.x + threadIdx.x;
  if (g < E) {
    int d = dst[g];
    int p = atomicAdd(&cursor[d], 1);
    unsigned long long pk =
        ((unsigned long long)(unsigned)__float_as_int(w[g]) << 32) |
        (unsigned long long)(unsigned)src[g];
    __builtin_nontemporal_store((long long)pk, (long long*)&eld[p]);
  }
}

// ---------------- fused layer kernel: GEMM1 (h) -> LDS fragments -> GEMM2 (kqv)
// TWO adjacent 16-row tiles per wave (shared B fragments). No intra-wave fences
// (per-wave LDS, in-order DS ops; compiler auto-inserts data-use waits).
template <int FIRST>
__global__ __launch_bounds__(256) void fused_layer(
    const float* __restrict__ x, const _Float16* __restrict__ aggp,
    const _Float16* __restrict__ Wg1, const float* __restrict__ bias,
    const float* __restrict__ skipv, _Float16* __restrict__ hbuf,
    const _Float16* __restrict__ Wcat_l,
    _Float16* __restrict__ kwmv, _Float16* __restrict__ qbuf, int M) {
  int tid = threadIdx.x;
  int wave = tid >> 6, lane = tid & 63;
  int l16 = lane & 15, q = lane >> 4;
  int g = q, mloc = l16;
  int t0 = (blockIdx.x * 4 + wave) * 2;

  __shared__ _Float16 htile_s[4][2][2048];
  __shared__ float ldsT_s[4][16 * 68];
  float* myT = ldsT_s[wave];

  float alpha = 1.f, beta = 0.f;
  if (!FIRST) {
    float sv = *skipv;
    alpha = 1.f / (1.f + __expf(-sv));
    beta = 1.f - alpha;
  }

  floatx4 acc[2][8];
#pragma unroll
  for (int t = 0; t < 2; t++)
#pragma unroll
    for (int nt = 0; nt < 8; nt++) acc[t][nt] = (floatx4){0.f, 0.f, 0.f, 0.f};

#pragma unroll
  for (int kc = 0; kc < 4; kc++) {
    half8v a0, a1;
#pragma unroll
    for (int t = 0; t < 2; t++) {
      int tile = t0 + t;
      int tileC = (tile * 16 < M) ? tile : 0;
      half8v av;
      if (FIRST) {
        int row = min(tile * 16 + l16, M - 1);
        const float* p = x + (size_t)row * 128 + kc * 32 + q * 8;
        float4 u0 = *(const float4*)p, u1 = *(const float4*)(p + 4);
        float f[8] = {u0.x, u0.y, u0.z, u0.w, u1.x, u1.y, u1.z, u1.w};
#pragma unroll
        for (int i = 0; i < 8; i++) av[i] = (_Float16)f[i];
      } else {
        av = *(const half8v*)(aggp + (size_t)tileC * 2048 + (kc << 9) + lane * 8);
      }
      if (t == 0) a0 = av; else a1 = av;
    }
#pragma unroll
    for (int nt = 0; nt < 8; nt++) {
      half8v b = *(const half8v*)(Wg1 + (size_t)nt * 2048 + (kc << 9) + lane * 8);
      acc[0][nt] = __builtin_amdgcn_mfma_f32_16x16x32_f16(a0, b, acc[0][nt], 0, 0, 0);
      acc[1][nt] = __builtin_amdgcn_mfma_f32_16x16x32_f16(a1, b, acc[1][nt], 0, 0, 0);
    }
  }

#pragma unroll
  for (int t = 0; t < 2; t++) {
    int tile = t0 + t;
    bool alive = tile * 16 < M;
    int tileC = alive ? tile : 0;
#pragma unroll
    for (int p = 0; p < 2; p++) {
#pragma unroll
      for (int ntl = 0; ntl < 4; ntl++)
#pragma unroll
        for (int r = 0; r < 4; r++)
          myT[(q * 4 + r) * 68 + ntl * 16 + l16] = acc[t][p * 4 + ntl][r];
#pragma unroll
      for (int kc2 = 0; kc2 < 2; kc2++) {
        const float* rp = myT + mloc * 68 + kc2 * 32 + g * 8;
        floatx4 v0 = *(const floatx4*)rp;
        floatx4 v1 = *(const floatx4*)(rp + 4);
        float vals[8] = {v0[0], v0[1], v0[2], v0[3], v1[0], v1[1], v1[2], v1[3]};
        int col0 = p * 64 + kc2 * 32 + g * 8;
        size_t pbaseL = ((size_t)(tileC * 4 + (col0 >> 5)) << 9) + (size_t)lane * 8;
        if (FIRST) {
          float4 bb0 = *(const float4*)&bias[col0];
          float4 bb1 = *(const float4*)&bias[col0 + 4];
          float bbv[8] = {bb0.x, bb0.y, bb0.z, bb0.w, bb1.x, bb1.y, bb1.z, bb1.w};
#pragma unroll
          for (int j = 0; j < 8; j++) vals[j] = fmaxf(vals[j] + bbv[j], 0.f);
        } else {
          half8v hv = *(const half8v*)(hbuf + pbaseL);
#pragma unroll
          for (int j = 0; j < 8; j++)
            vals[j] = fmaxf(alpha * vals[j] + beta * (float)hv[j], 0.f);
        }
        half8v h8;
#pragma unroll
        for (int j = 0; j < 8; j++) h8[j] = (_Float16)vals[j];
        *(half8v*)(&htile_s[wave][t][0] + (((p * 2 + kc2) << 9) + (g << 7) + (mloc << 3))) = h8;
        if (alive) *(half8v*)(hbuf + pbaseL) = h8;
      }
    }
  }

  for (int c = 0; c < 6; c++) {
    floatx4 acc2[2][4];
#pragma unroll
    for (int t = 0; t < 2; t++)
#pragma unroll
      for (int nt = 0; nt < 4; nt++) acc2[t][nt] = (floatx4){0.f, 0.f, 0.f, 0.f};
#pragma unroll
    for (int kc = 0; kc < 4; kc++) {
      half8v af0 = *(const half8v*)(&htile_s[wave][0][0] + ((kc << 9) + lane * 8));
      half8v af1 = *(const half8v*)(&htile_s[wave][1][0] + ((kc << 9) + lane * 8));
#pragma unroll
      for (int nt = 0; nt < 4; nt++) {
        half8v b = *(const half8v*)(Wcat_l + (size_t)(c * 4 + nt) * 2048 + (kc << 9) + lane * 8);
        acc2[0][nt] = __builtin_amdgcn_mfma_f32_16x16x32_f16(af0, b, acc2[0][nt], 0, 0, 0);
        acc2[1][nt] = __builtin_amdgcn_mfma_f32_16x16x32_f16(af1, b, acc2[1][nt], 0, 0, 0);
      }
    }
#pragma unroll
    for (int t = 0; t < 2; t++) {
      int tile = t0 + t;
      bool alive = tile * 16 < M;
      int m0 = tile * 16;
#pragma unroll
      for (int ntl = 0; ntl < 4; ntl++)
#pragma unroll
        for (int r = 0; r < 4; r++)
          myT[(q * 4 + r) * 68 + ntl * 16 + l16] = acc2[t][ntl][r];
      if (alive) {
        int row = m0 + mloc;
#pragma unroll
        for (int kc2 = 0; kc2 < 2; kc2++) {
          const float* rp = myT + mloc * 68 + kc2 * 32 + g * 8;
          floatx4 v0 = *(const floatx4*)rp;
          floatx4 v1 = *(const floatx4*)(rp + 4);
          int col0 = c * 64 + kc2 * 32 + g * 8;
          int region = col0 >> 7;  // 0 kw, 1 q, 2 mv
          if (region == 1) {
            half8v h8;
#pragma unroll
            for (int j = 0; j < 4; j++) {
              h8[j] = (_Float16)v0[j];
              h8[j + 4] = (_Float16)v1[j];
            }
            *(half8v*)&qbuf[(size_t)row * 128 + (col0 - 128)] = h8;
          } else {
            int cc = col0 & 127;
            size_t base = (size_t)row * 256 + (size_t)(cc >> 2) * 8 + (region == 2 ? 4 : 0);
            half4v h0, h1;
#pragma unroll
            for (int j = 0; j < 4; j++) {
              h0[j] = (_Float16)v0[j];
              h1[j] = (_Float16)v1[j];
            }
            *(half4v*)&kwmv[base] = h0;
            *(half4v*)&kwmv[base + 8] = h1;
          }
        }
      }
    }
  }
}

// ---------------- last Wa GEMM (2 tiles/wave)
__global__ __launch_bounds__(256) void gemm_last(
    const _Float16* __restrict__ aggp, const _Float16* __restrict__ Wg1,
    const float* __restrict__ skipv, const _Float16* __restrict__ hbuf,
    float* __restrict__ hfinal, _Float16* __restrict__ hrow, int M) {
  int tid = threadIdx.x;
  int wave = tid >> 6, lane = tid & 63;
  int l16 = lane & 15, q = lane >> 4;
  int g = q, mloc = l16;
  int t0 = (blockIdx.x * 4 + wave) * 2;

  __shared__ float ldsT_s[4][16 * 68];
  float* myT = ldsT_s[wave];

  float sv = *skipv;
  float alpha = 1.f / (1.f + __expf(-sv));
  float beta = 1.f - alpha;

  floatx4 acc[2][8];
#pragma unroll
  for (int t = 0; t < 2; t++)
#pragma unroll
    for (int nt = 0; nt < 8; nt++) acc[t][nt] = (floatx4){0.f, 0.f, 0.f, 0.f};

#pragma unroll
  for (int kc = 0; kc < 4; kc++) {
    int tC0 = (t0 * 16 < M) ? t0 : 0;
    int tC1 = ((t0 + 1) * 16 < M) ? (t0 + 1) : 0;
    half8v a0 = *(const half8v*)(aggp + (size_t)tC0 * 2048 + (kc << 9) + lane * 8);
    half8v a1 = *(const half8v*)(aggp + (size_t)tC1 * 2048 + (kc << 9) + lane * 8);
#pragma unroll
    for (int nt = 0; nt < 8; nt++) {
      half8v b = *(const half8v*)(Wg1 + (size_t)nt * 2048 + (kc << 9) + lane * 8);
      acc[0][nt] = __builtin_amdgcn_mfma_f32_16x16x32_f16(a0, b, acc[0][nt], 0, 0, 0);
      acc[1][nt] = __builtin_amdgcn_mfma_f32_16x16x32_f16(a1, b, acc[1][nt], 0, 0, 0);
    }
  }

#pragma unroll
  for (int t = 0; t < 2; t++) {
    int tile = t0 + t;
    bool alive = tile * 16 < M;
    int m0 = tile * 16;
#pragma unroll
    for (int p = 0; p < 2; p++) {
#pragma unroll
      for (int ntl = 0; ntl < 4; ntl++)
#pragma unroll
        for (int r = 0; r < 4; r++)
          myT[(q * 4 + r) * 68 + ntl * 16 + l16] = acc[t][p * 4 + ntl][r];
      if (alive) {
        int row = m0 + mloc;
#pragma unroll
        for (int kc2 = 0; kc2 < 2; kc2++) {
          const float* rp = myT + mloc * 68 + kc2 * 32 + g * 8;
          floatx4 v0 = *(const floatx4*)rp;
          floatx4 v1 = *(const floatx4*)(rp + 4);
          float vals[8] = {v0[0], v0[1], v0[2], v0[3], v1[0], v1[1], v1[2], v1[3]};
          int col0 = p * 64 + kc2 * 32 + g * 8;
          size_t pbase = ((size_t)(tile * 4 + (col0 >> 5)) << 9) + (size_t)lane * 8;
          half8v hv = *(const half8v*)(hbuf + pbase);
#pragma unroll
          for (int j = 0; j < 8; j++) vals[j] = alpha * vals[j] + beta * (float)hv[j];
          *(float4*)&hfinal[(size_t)row * 128 + col0] =
              make_float4(vals[0], vals[1], vals[2], vals[3]);
          *(float4*)&hfinal[(size_t)row * 128 + col0 + 4] =
              make_float4(vals[4], vals[5], vals[6], vals[7]);
          half8v h8;
#pragma unroll
          for (int j = 0; j < 8; j++) h8[j] = (_Float16)vals[j];
          *(half8v*)&hrow[(size_t)row * 128 + col0] = h8;
        }
      }
    }
  }
}

// ---------------- fused predictor (2 tiles/wave)
__global__ __launch_bounds__(256) void pred_fused(
    const _Float16* __restrict__ hrow,
    const int* __restrict__ ps, const int* __restrict__ pd,
    const int* __restrict__ ns, const int* __restrict__ nd,
    const _Float16* __restrict__ W1f, const float* __restrict__ b1,
    const _Float16* __restrict__ W2f, const float* __restrict__ b2,
    const float* __restrict__ W3, const float* __restrict__ b3,
    float* __restrict__ outd, int M) {
  int tid = threadIdx.x;
  int wave = tid >> 6, lane = tid & 63;
  int l16 = lane & 15, q = lane >> 4;
  int g = q, mloc = l16;
  int t0 = (blockIdx.x * 4 + wave) * 2;

  __shared__ _Float16 t1_s[4][2][1024];
  __shared__ float ldsT_s[4][16 * 68];
  float* myT = ldsT_s[wave];

  int pa[2], pb[2];
#pragma unroll
  for (int t = 0; t < 2; t++) {
    int gr = min((t0 + t) * 16 + l16, M - 1);
    bool pos = gr < N_PAIRS;
    int idx = pos ? gr : gr - N_PAIRS;
    pa[t] = pos ? ps[idx] : ns[idx];
    pb[t] = pos ? pd[idx] : nd[idx];
  }

  floatx4 acc1[2][4];
#pragma unroll
  for (int t = 0; t < 2; t++)
#pragma unroll
    for (int nt = 0; nt < 4; nt++) acc1[t][nt] = (floatx4){0.f, 0.f, 0.f, 0.f};

#pragma unroll
  for (int kc = 0; kc < 4; kc++) {
    int kbase = kc * 32 + q * 8;
    half8v a0, a1;
#pragma unroll
    for (int t = 0; t < 2; t++) {
      half8v ha = *(const half8v*)(hrow + (size_t)pa[t] * 128 + kbase);
      half8v hb = *(const half8v*)(hrow + (size_t)pb[t] * 128 + kbase);
      half8v av = ha * hb;
      if (t == 0) a0 = av; else a1 = av;
    }
#pragma unroll
    for (int nt = 0; nt < 4; nt++) {
      half8v b = *(const half8v*)(W1f + (size_t)nt * 2048 + (kc << 9) + lane * 8);
      acc1[0][nt] = __builtin_amdgcn_mfma_f32_16x16x32_f16(a0, b, acc1[0][nt], 0, 0, 0);
      acc1[1][nt] = __builtin_amdgcn_mfma_f32_16x16x32_f16(a1, b, acc1[1][nt], 0, 0, 0);
    }
  }

#pragma unroll
  for (int t = 0; t < 2; t++) {
#pragma unroll
    for (int ntl = 0; ntl < 4; ntl++)
#pragma unroll
      for (int r = 0; r < 4; r++)
        myT[(q * 4 + r) * 68 + ntl * 16 + l16] = acc1[t][ntl][r];
#pragma unroll
    for (int kc2 = 0; kc2 < 2; kc2++) {
      const float* rp = myT + mloc * 68 + kc2 * 32 + g * 8;
      floatx4 v0 = *(const floatx4*)rp;
      floatx4 v1 = *(const floatx4*)(rp + 4);
      float vals[8] = {v0[0], v0[1], v0[2], v0[3], v1[0], v1[1], v1[2], v1[3]};
      int col0 = kc2 * 32 + g * 8;
      float4 bb0 = *(const float4*)&b1[col0];
      float4 bb1 = *(const float4*)&b1[col0 + 4];
      float bbv[8] = {bb0.x, bb0.y, bb0.z, bb0.w, bb1.x, bb1.y, bb1.z, bb1.w};
      half8v h8;
#pragma unroll
      for (int j = 0; j < 8; j++) {
        float v = vals[j] + bbv[j];
        v = v > 0.f ? v : 0.2f * v;
        h8[j] = (_Float16)v;
      }
      *(half8v*)(&t1_s[wave][t][0] + ((kc2 << 9) + (g << 7) + (mloc << 3))) = h8;
    }
  }

  floatx4 acc2[2][2];
#pragma unroll
  for (int t = 0; t < 2; t++)
#pragma unroll
    for (int nt = 0; nt < 2; nt++) acc2[t][nt] = (floatx4){0.f, 0.f, 0.f, 0.f};
#pragma unroll
  for (int kc = 0; kc < 2; kc++) {
    half8v af0 = *(const half8v*)(&t1_s[wave][0][0] + ((kc << 9) + lane * 8));
    half8v af1 = *(const half8v*)(&t1_s[wave][1][0] + ((kc << 9) + lane * 8));
#pragma unroll
    for (int nt = 0; nt < 2; nt++) {
      half8v b = *(const half8v*)(W2f + (size_t)nt * 1024 + (kc << 9) + lane * 8);
      acc2[0][nt] = __builtin_amdgcn_mfma_f32_16x16x32_f16(af0, b, acc2[0][nt], 0, 0, 0);
      acc2[1][nt] = __builtin_amdgcn_mfma_f32_16x16x32_f16(af1, b, acc2[1][nt], 0, 0, 0);
    }
  }

  float bw[2], wv[2];
#pragma unroll
  for (int nt = 0; nt < 2; nt++) {
    int col = nt * 16 + l16;
    bw[nt] = b2[col];
    wv[nt] = W3[col];
  }
  float b3v = b3[0];
#pragma unroll
  for (int t = 0; t < 2; t++) {
    int m0 = (t0 + t) * 16;
    bool alive = m0 < M;
#pragma unroll
    for (int r = 0; r < 4; r++) {
      float partial = 0.f;
#pragma unroll
      for (int nt = 0; nt < 2; nt++) {
        float v = acc2[t][nt][r] + bw[nt];
        v = v > 0.f ? v : 0.2f * v;
        partial += v * wv[nt];
      }
      partial += __shfl_xor(partial, 1);
      partial += __shfl_xor(partial, 2);
      partial += __shfl_xor(partial, 4);
      partial += __shfl_xor(partial, 8);
      int row = m0 + q * 4 + r;
      if (l16 == 0 && alive && row < M) outd[row] = partial + b3v;
    }
  }
}

// ---------------- per-destination online-softmax aggregation [R2 best, unchanged]
__global__ __launch_bounds__(256) void edge_agg_kernel(
    const _Float16* __restrict__ kwmv, const _Float16* __restrict__ qbuf,
    const int* __restrict__ poffs, const int2* __restrict__ eld,
    const int* __restrict__ perm,
    _Float16* __restrict__ agg, int n) {
  int hw = (blockIdx.x * 256 + threadIdx.x) >> 5;
  int stride = gridDim.x << 3;
  int c4 = threadIdx.x & 31;
  int ch = c4 << 2;
  for (int gw = hw; gw < n; gw += stride) {
    int node = perm[gw];
    half4v qv = *(const half4v*)&qbuf[(size_t)node * 128 + ch];
    half2v q01 = {qv[0], qv[1]}, q23 = {qv[2], qv[3]};
    float m = -1e30f, s = 0.f;
    float a0 = 0.f, a1 = 0.f, a2 = 0.f, a3 = 0.f;
    int beg = poffs[node], end = poffs[node + 1];
    if (beg < end) {
      int2 e0[8], e1[8], e2[8];
      half8v g0[8], g1[8];
#pragma unroll
      for (int i = 0; i < 8; i++) e0[i] = eld[beg + i];
#pragma unroll
      for (int i = 0; i < 8; i++)
        g0[i] = *(const half8v*)&kwmv[(size_t)max(e0[i].x, 0) * 256 + (size_t)c4 * 8];
#pragma unroll
      for (int i = 0; i < 8; i++) e1[i] = eld[beg + 8 + i];
      int j = beg;
      for (; j + 8 < end; j += 8) {
#pragma unroll
        for (int i = 0; i < 8; i++)
          g1[i] = *(const half8v*)&kwmv[(size_t)max(e1[i].x, 0) * 256 + (size_t)c4 * 8];
#pragma unroll
        for (int i = 0; i < 8; i++) e2[i] = eld[j + 16 + i];
        float p[8];
#pragma unroll
        for (int i = 0; i < 8; i++) {
          half2v k01 = {g0[i][0], g0[i][1]}, k23 = {g0[i][2], g0[i][3]};
          float d = __builtin_amdgcn_fdot2(
              k01, q01, __builtin_amdgcn_fdot2(k23, q23, 0.f, false), false);
          d += __shfl_xor(d, 1);
          d += __shfl_xor(d, 2);
          p[i] = (e0[i].x >= 0) ? d : -1e30f;
        }
        float nm = m;
#pragma unroll
        for (int i = 0; i < 8; i++) nm = fmaxf(nm, p[i]);
        float sc = __expf(m - nm);
        float t[8];
        float ssum = 0.f;
#pragma unroll
        for (int i = 0; i < 8; i++) {
          t[i] = __expf(p[i] - nm);
          ssum += t[i];
        }
        s = s * sc + ssum;
        a0 *= sc; a1 *= sc; a2 *= sc; a3 *= sc;
#pragma unroll
        for (int i = 0; i < 8; i++) {
          float w = (e0[i].x >= 0) ? __int_as_float(e0[i].y) : 0.f;
          float f = t[i] * w;
          a0 += f * (float)g0[i][4];
          a1 += f * (float)g0[i][5];
          a2 += f * (float)g0[i][6];
          a3 += f * (float)g0[i][7];
        }
        m = nm;
#pragma unroll
        for (int i = 0; i < 8; i++) {
          e0[i] = e1[i];
          e1[i] = e2[i];
          g0[i] = g1[i];
        }
      }
      {
        float p[8];
#pragma unroll
        for (int i = 0; i < 8; i++) {
          half2v k01 = {g0[i][0], g0[i][1]}, k23 = {g0[i][2], g0[i][3]};
          float d = __builtin_amdgcn_fdot2(
              k01, q01, __builtin_amdgcn_fdot2(k23, q23, 0.f, false), false);
          d += __shfl_xor(d, 1);
          d += __shfl_xor(d, 2);
          p[i] = (e0[i].x >= 0) ? d : -1e30f;
        }
        float nm = m;
#pragma unroll
        for (int i = 0; i < 8; i++) nm = fmaxf(nm, p[i]);
        float sc = __expf(m - nm);
        float t[8];
        float ssum = 0.f;
#pragma unroll
        for (int i = 0; i < 8; i++) {
          t[i] = __expf(p[i] - nm);
          ssum += t[i];
        }
        s = s * sc + ssum;
        a0 *= sc; a1 *= sc; a2 *= sc; a3 *= sc;
#pragma unroll
        for (int i = 0; i < 8; i++) {
          float w = (e0[i].x >= 0) ? __int_as_float(e0[i].y) : 0.f;
          float f = t[i] * w;
          a0 += f * (float)g0[i][4];
          a1 += f * (float)g0[i][5];
          a2 += f * (float)g0[i][6];
          a3 += f * (float)g0[i][7];
        }
      }
    }
    float inv = (s > 0.f) ? 1.f / s : 0.f;
    half4v out4;
    out4[0] = (_Float16)(a0 * inv);
    out4[1] = (_Float16)(a1 * inv);
    out4[2] = (_Float16)(a2 * inv);
    out4[3] = (_Float16)(a3 * inv);
    *(half4v*)&agg[packA(node, ch, 128)] = out4;
  }
}

extern "C" void kernel_launch(void* const* d_in, const int* in_sizes, int n_in,
                              void* d_out, int out_size, void* d_ws, size_t ws_size,
                              hipStream_t stream) {
  const float* x        = (const float*)d_in[0];
  const int*   edge_src = (const int*)d_in[1];
  const int*   edge_dst = (const int*)d_in[2];
  const float* edge_w   = (const float*)d_in[3];
  const int*   pos_src  = (const int*)d_in[4];
  const int*   pos_dst  = (const int*)d_in[5];
  const int*   neg_src  = (const int*)d_in[6];
  const int*   neg_dst  = (const int*)d_in[7];
  const float* W_in     = (const float*)d_in[8];
  const float* b_in     = (const float*)d_in[9];
  const float* Wk       = (const float*)d_in[10];
  const float* Wq       = (const float*)d_in[11];
  const float* Wv       = (const float*)d_in[12];
  const float* att_w    = (const float*)d_in[13];
  const float* msg_w    = (const float*)d_in[14];
  const float* pri      = (const float*)d_in[15];
  const float* Wa       = (const float*)d_in[16];
  const float* skip     = (const float*)d_in[17];
  const float* W1       = (const float*)d_in[18];
  const float* b1       = (const float*)d_in[19];
  const float* W2       = (const float*)d_in[20];
  const float* b2       = (const float*)d_in[21];
  const float* W3       = (const float*)d_in[22];
  const float* b3       = (const float*)d_in[23];
  float* out = (float*)d_out;

  // ---- workspace layout (bytes), ~91 MB
  char* W = (char*)d_ws;
  _Float16*  qbuf   = (_Float16*)(W + 0);          // 12,800,000
  _Float16*  kwmv   = (_Float16*)(W + 12800000);   // 25,600,000
  _Float16*  hbuf   = (_Float16*)(W + 38400000);   // 12,800,000 (packed h)
  _Float16*  agg    = (_Float16*)(W + 51200000);   // 12,800,000
  _Float16*  Wint   = (_Float16*)(W + 64000000);   // 32,768
  _Float16*  Wcat   = (_Float16*)(W + 64032768);   // 294,912
  _Float16*  Waf    = (_Float16*)(W + 64327680);   // 98,304
  _Float16*  W1f    = (_Float16*)(W + 64425984);   // 16,384
  _Float16*  W2f    = (_Float16*)(W + 64442368);   // 8,192
  int2*      eld    = (int2*)(W + 64450560);       // 12,800,000 (padded-8 edges)
  int*       deg    = (int*)(W + 77250560);        // 200,000
  int*       bh     = (int*)(W + 77450560);        // 1,024   (adjacent: one memset)
  int*       balloc = (int*)(W + 77451584);        // 1,024
  int*       poffs  = (int*)(W + 77452608);        // 200,016
  int*       cursor = (int*)(W + 77652624);        // 200,000
  int*       perm   = (int*)(W + 77852624);        // 200,000
  int*       bsum   = (int*)(W + 78052624);        // 1,024
  _Float16*  hrow   = (_Float16*)(W + 78054912);   // 12,800,000 (fp16 row-major hfinal)
  float* hfinal = out + 2 * N_PAIRS;

  hipMemsetAsync(deg, 0, 202048, stream);
  hipMemsetAsync(eld, 0xFF, 9600000, stream);

  prep_fused<<<4005, 256, 0, stream>>>(W_in, Wk, Wq, Wv, att_w, msg_w, pri, Wa, W1, W2,
                                       Wint, Wcat, Waf, W1f, W2f,
                                       edge_dst, deg, N_EDGES);
  scanA_kernel<<<196, 256, 0, stream>>>(deg, poffs, bsum, bh, N_NODES);
  scanC_fused<<<196, 256, 0, stream>>>(poffs, bsum, bh, balloc, deg, cursor, perm,
                                       196, N_NODES);
  scatter_kernel<<<(N_EDGES + 255) / 256, 256, 0, stream>>>(
      edge_src, edge_dst, edge_w, cursor, eld, N_EDGES);

  // layer 0
  fused_layer<1><<<391, 256, 0, stream>>>(x, nullptr, Wint, b_in, nullptr, hbuf,
                                          Wcat, kwmv, qbuf, N_NODES);
  edge_agg_kernel<<<2048, 256, 0, stream>>>(kwmv, qbuf, poffs, eld, perm, agg, N_NODES);
  // layer 1
  fused_layer<0><<<391, 256, 0, stream>>>(nullptr, agg, Waf, nullptr, skip + 0, hbuf,
                                          Wcat + 49152, kwmv, qbuf, N_NODES);
  edge_agg_kernel<<<2048, 256, 0, stream>>>(kwmv, qbuf, poffs, eld, perm, agg, N_NODES);
  // layer 2
  fused_layer<0><<<391, 256, 0, stream>>>(nullptr, agg, Waf + 16384, nullptr, skip + 1,
                                          hbuf, Wcat + 98304, kwmv, qbuf, N_NODES);
  edge_agg_kernel<<<2048, 256, 0, stream>>>(kwmv, qbuf, poffs, eld, perm, agg, N_NODES);
  // final
  gemm_last<<<391, 256, 0, stream>>>(agg, Waf + 32768, skip + 2, hbuf,
                                     hfinal, hrow, N_NODES);
  pred_fused<<<1563, 256, 0, stream>>>(hrow, pos_src, pos_dst, neg_src, neg_dst,
                                       W1f, b1, W2f, b2, W3, b3, out, 2 * N_PAIRS);
}